// Round 1
// baseline (37.008 us; speedup 1.0000x reference)
//
#include <hip/hip_runtime.h>

#define HW_TOT 3136   // 56*56
#define KK     196
#define BCN    256    // B*C
#define GB     8      // (b,c) slices per block
#define NSEG   16     // hw segments
#define CH     196    // hw chunk staged in LDS (= HW_TOT/NSEG)
#define LOG2E  1.4426950408889634f

// grid = (nseg, BCN/GB), block = 256.
// Lane t handles RF kernel k = t (t < 196); computes partial sums of
// exp(u[bc,hw] * rfs[hw,k]) over its hw segment for GB consecutive bc's.
__global__ __launch_bounds__(256, 2) void rf_pool_main(
    const float* __restrict__ u, const float* __restrict__ rfs,
    float* __restrict__ part,   // [nseg][BCN][KK]; unused if nseg==1
    float* __restrict__ out,    // used when nseg==1
    int nseg)
{
    const int seg = blockIdx.x;
    const int grp = blockIdx.y;
    const int tid = threadIdx.x;
    const int bc0 = grp * GB;
    const int hw_per_seg = HW_TOT / nseg;
    const int hw0 = seg * hw_per_seg;

    __shared__ __align__(16) float u_lds[GB][CH];

    float sum[GB];
    #pragma unroll
    for (int g = 0; g < GB; ++g) sum[g] = 0.0f;

    for (int c0 = 0; c0 < hw_per_seg; c0 += CH) {
        const int base = hw0 + c0;
        __syncthreads();
        if (tid < CH) {
            #pragma unroll
            for (int g = 0; g < GB; ++g)
                u_lds[g][tid] = u[(bc0 + g) * HW_TOT + base + tid] * LOG2E;
        }
        __syncthreads();
        if (tid < KK) {
            const float* rp = rfs + (long)base * KK + tid;
            for (int h = 0; h < CH; h += 4) {
                float rf0 = rp[(h + 0) * KK];
                float rf1 = rp[(h + 1) * KK];
                float rf2 = rp[(h + 2) * KK];
                float rf3 = rp[(h + 3) * KK];
                #pragma unroll
                for (int g = 0; g < GB; ++g) {
                    float4 ug = *(const float4*)&u_lds[g][h];
                    sum[g] += __builtin_amdgcn_exp2f(ug.x * rf0);
                    sum[g] += __builtin_amdgcn_exp2f(ug.y * rf1);
                    sum[g] += __builtin_amdgcn_exp2f(ug.z * rf2);
                    sum[g] += __builtin_amdgcn_exp2f(ug.w * rf3);
                }
            }
        }
    }

    if (tid < KK) {
        if (nseg == 1) {
            #pragma unroll
            for (int g = 0; g < GB; ++g) {
                float s = sum[g];
                out[(bc0 + g) * KK + tid] = s / (s + 1.0f);
            }
        } else {
            #pragma unroll
            for (int g = 0; g < GB; ++g)
                part[((long)seg * BCN + (bc0 + g)) * KK + tid] = sum[g];
        }
    }
}

// Reduce the nseg partial sums and apply S/(S+1).
__global__ __launch_bounds__(256) void rf_pool_finalize(
    const float* __restrict__ part, float* __restrict__ out, int nseg)
{
    const int i = blockIdx.x * 256 + threadIdx.x;
    if (i < BCN * KK) {
        float s = 0.0f;
        for (int sg = 0; sg < nseg; ++sg)
            s += part[(long)sg * BCN * KK + i];
        out[i] = s / (s + 1.0f);
    }
}

extern "C" void kernel_launch(void* const* d_in, const int* in_sizes, int n_in,
                              void* d_out, int out_size, void* d_ws, size_t ws_size,
                              hipStream_t stream) {
    const float* u   = (const float*)d_in[0];   // (8,32,56,56) f32
    const float* rfs = (const float*)d_in[1];   // (56,56,196) f32
    float* out = (float*)d_out;                 // (8,32,196) f32

    const size_t need = (size_t)NSEG * BCN * KK * sizeof(float);
    if (ws_size >= need) {
        float* part = (float*)d_ws;
        dim3 grid(NSEG, BCN / GB);
        rf_pool_main<<<grid, 256, 0, stream>>>(u, rfs, part, out, NSEG);
        const int nout = BCN * KK;
        rf_pool_finalize<<<(nout + 255) / 256, 256, 0, stream>>>(part, out, NSEG);
    } else {
        // Fallback: no workspace split — single segment writes out directly.
        dim3 grid(1, BCN / GB);
        rf_pool_main<<<grid, 256, 0, stream>>>(u, rfs, nullptr, out, 1);
    }
}

// Round 2
// 35.916 us; speedup vs baseline: 1.0304x; 1.0304x over previous
//
#include <hip/hip_runtime.h>

#define HW    3136   // 56*56
#define KK    196
#define BCN   256    // B*C
#define NSEG  49     // hw segments of 64
#define LOG2E 1.4426950408889634f

// ---- Kernel A: transpose+scale u[bc][hw] -> uT2[hw/2][bc] (float2 = hw even/odd), *log2e
__global__ __launch_bounds__(256) void rf_transpose(const float* __restrict__ u,
                                                    float2* __restrict__ uT2) {
    __shared__ float tile[64][65];
    const int t  = threadIdx.x;
    const int h0 = blockIdx.x * 64;   // 49 hw tiles
    const int b0 = blockIdx.y * 64;   // 4 bc tiles
    const int c  = t & 63;
    const int r  = t >> 6;
    #pragma unroll
    for (int j = 0; j < 16; ++j)
        tile[r + 4*j][c] = u[(b0 + r + 4*j) * HW + h0 + c];
    __syncthreads();
    const int tw = t & 63;
    const int hb = t >> 6;            // 0..3
    #pragma unroll
    for (int i = 0; i < 8; ++i) {
        const int h2 = hb * 8 + i;    // 0..31
        float2 v;
        v.x = tile[tw][2*h2]     * LOG2E;
        v.y = tile[tw][2*h2 + 1] * LOG2E;
        uT2[(h0/2 + h2) * BCN + b0 + tw] = v;
    }
}

// ---- Kernel B: main. grid (49 kc, 49 seg), block 256 (lane = bc).
// acc[j] += exp2(u' * rf) over 64 hw per segment, 4 k's per block.
__global__ __launch_bounds__(256) void rf_main(const float2* __restrict__ uT2,
                                               const float* __restrict__ rfs,
                                               float* __restrict__ part) {
    const int kc  = blockIdx.x;           // 0..48
    const int seg = blockIdx.y;           // 0..48
    const int t   = threadIdx.x;          // bc
    const int k0  = kc * 4;
    const int h0  = seg * 64;
    float2 a0 = {0.f,0.f}, a1 = {0.f,0.f}, a2 = {0.f,0.f}, a3 = {0.f,0.f};
    const float2* up = uT2 + (h0/2) * BCN + t;
    const float*  rp = rfs + (long)h0 * KK + k0;
    #pragma unroll 8
    for (int hp = 0; hp < 32; ++hp) {
        const float2 uv = up[hp * BCN];
        const float4 r0 = *(const float4*)(rp + (2*hp)     * KK);  // wave-uniform
        const float4 r1 = *(const float4*)(rp + (2*hp + 1) * KK);  // wave-uniform
        a0.x += __builtin_amdgcn_exp2f(uv.x * r0.x);
        a0.y += __builtin_amdgcn_exp2f(uv.y * r1.x);
        a1.x += __builtin_amdgcn_exp2f(uv.x * r0.y);
        a1.y += __builtin_amdgcn_exp2f(uv.y * r1.y);
        a2.x += __builtin_amdgcn_exp2f(uv.x * r0.z);
        a2.y += __builtin_amdgcn_exp2f(uv.y * r1.z);
        a3.x += __builtin_amdgcn_exp2f(uv.x * r0.w);
        a3.y += __builtin_amdgcn_exp2f(uv.y * r1.w);
    }
    float* pp = part + ((long)seg * KK + k0) * BCN + t;
    pp[0]       = a0.x + a0.y;
    pp[BCN]     = a1.x + a1.y;
    pp[2*BCN]   = a2.x + a2.y;
    pp[3*BCN]   = a3.x + a3.y;
}

// ---- Kernel C: reduce over segments, p = S/(1+S), scatter to out[bc][k].
__global__ __launch_bounds__(256) void rf_fin(const float* __restrict__ part,
                                              float* __restrict__ out) {
    const int k = blockIdx.x;    // 0..195
    const int t = threadIdx.x;   // bc
    float s = 0.f;
    #pragma unroll
    for (int seg = 0; seg < NSEG; ++seg)
        s += part[((long)seg * KK + k) * BCN + t];
    out[t * KK + k] = s / (1.0f + s);
}

// ---- Fallback (no workspace): R1-style monolithic, lane = k.
__global__ __launch_bounds__(256) void rf_pool_fallback(const float* __restrict__ u,
                                                        const float* __restrict__ rfs,
                                                        float* __restrict__ out) {
    const int grp = blockIdx.x;
    const int tid = threadIdx.x;
    const int bc0 = grp * 8;
    __shared__ __align__(16) float u_lds[8][196];
    float sum[8];
    #pragma unroll
    for (int g = 0; g < 8; ++g) sum[g] = 0.0f;
    for (int base = 0; base < HW; base += 196) {
        __syncthreads();
        if (tid < 196) {
            #pragma unroll
            for (int g = 0; g < 8; ++g)
                u_lds[g][tid] = u[(bc0 + g) * HW + base + tid] * LOG2E;
        }
        __syncthreads();
        if (tid < KK) {
            const float* rp = rfs + (long)base * KK + tid;
            for (int h = 0; h < 196; h += 4) {
                float rf0 = rp[(h + 0) * KK];
                float rf1 = rp[(h + 1) * KK];
                float rf2 = rp[(h + 2) * KK];
                float rf3 = rp[(h + 3) * KK];
                #pragma unroll
                for (int g = 0; g < 8; ++g) {
                    float4 ug = *(const float4*)&u_lds[g][h];
                    sum[g] += __builtin_amdgcn_exp2f(ug.x * rf0);
                    sum[g] += __builtin_amdgcn_exp2f(ug.y * rf1);
                    sum[g] += __builtin_amdgcn_exp2f(ug.z * rf2);
                    sum[g] += __builtin_amdgcn_exp2f(ug.w * rf3);
                }
            }
        }
    }
    if (tid < KK) {
        #pragma unroll
        for (int g = 0; g < 8; ++g) {
            float s = sum[g];
            out[(bc0 + g) * KK + tid] = s / (s + 1.0f);
        }
    }
}

extern "C" void kernel_launch(void* const* d_in, const int* in_sizes, int n_in,
                              void* d_out, int out_size, void* d_ws, size_t ws_size,
                              hipStream_t stream) {
    const float* u   = (const float*)d_in[0];   // (8,32,56,56) f32
    const float* rfs = (const float*)d_in[1];   // (56,56,196) f32
    float* out = (float*)d_out;                 // (8,32,196) f32

    const size_t part_off = 4u << 20;                                  // 4 MB
    const size_t need = part_off + (size_t)NSEG * KK * BCN * sizeof(float);
    if (ws_size >= need) {
        float2* uT2 = (float2*)d_ws;                                   // 3.2 MB
        float*  part = (float*)((char*)d_ws + part_off);               // 9.8 MB
        rf_transpose<<<dim3(49, 4), 256, 0, stream>>>(u, uT2);
        rf_main<<<dim3(49, NSEG), 256, 0, stream>>>(uT2, rfs, part);
        rf_fin<<<KK, 256, 0, stream>>>(part, out);
    } else {
        rf_pool_fallback<<<BCN / 8, 256, 0, stream>>>(u, rfs, out);
    }
}